// Round 1
// baseline (1514.579 us; speedup 1.0000x reference)
//
#include <hip/hip_runtime.h>
#include <hip/hip_bf16.h>
#include <float.h>

// Problem constants (h=1, b=32, n=2048, d=256, c=2048)
#define N_TOK 65536
#define DIM   256
#define CODES 2048
#define DECAY 0.8f
#define EPSV  1e-5f

// Output offsets (floats) in d_out, concatenated in reference return order
#define OUT_Q    ((size_t)0)            // quantize: 16777216
#define OUT_IND  ((size_t)16777216)     // embed_ind: 65536 (written as float)
#define OUT_DIST ((size_t)16842752)     // dist: 134217728
#define OUT_NEMB ((size_t)151060480)    // new_embed: 524288
#define OUT_NCS  ((size_t)151584768)    // new_cluster_size: 2048
#define OUT_NEA  ((size_t)151586816)    // new_embed_avg: 524288

// Workspace layout (float units)
#define WS_E2    ((size_t)0)          // 2048
#define WS_X2    ((size_t)2048)       // 65536
#define WS_BINS  ((size_t)67584)      // 2048
#define WS_ESUM  ((size_t)69632)      // 524288
#define WS_SMOO  ((size_t)593920)     // 2048
#define WS_INDI  ((size_t)595968)     // 65536 (int32)

// ---------------- row sum-of-squares: one wave per 256-float row ----------------
__global__ void k_rowsq(const float* __restrict__ in, float* __restrict__ out, int rows) {
    int gid  = blockIdx.x * blockDim.x + threadIdx.x;
    int w    = gid >> 6;
    int lane = threadIdx.x & 63;
    if (w >= rows) return;
    float4 v = reinterpret_cast<const float4*>(in + (size_t)w * DIM)[lane];
    float s = v.x * v.x + v.y * v.y + v.z * v.z + v.w * v.w;
    #pragma unroll
    for (int m = 32; m >= 1; m >>= 1) s += __shfl_xor(s, m);
    if (lane == 0) out[w] = s;
}

// ---------------- main: dist + argmin(sq) -----------------------------------
// Block: 256 threads = 16(ty) x 16(tx). Tile: 64 tokens x 64 codes, K-chunk 32.
// Each thread owns a 4x4 micro-tile (tokens ty*4+i, codes cc+tx*4+j).
#define TN 64
#define TC 64
#define KB 32
__launch_bounds__(256)
__global__ void k_main(const float* __restrict__ x, const float* __restrict__ embed,
                       const float* __restrict__ x2, const float* __restrict__ e2,
                       float* __restrict__ dist, float* __restrict__ ind_f,
                       int* __restrict__ ind_i) {
    __shared__ float xt[KB][TN + 4];   // row stride 68 floats = 272B (16B aligned)
    __shared__ float et[KB][TC + 4];
    const int tid = threadIdx.x;
    const int ty = tid >> 4, tx = tid & 15;
    const int n0 = blockIdx.x * TN;

    float myx2[4];
    #pragma unroll
    for (int i = 0; i < 4; ++i) myx2[i] = x2[n0 + ty * 4 + i];

    float bsq[4];
    int   bidx[4];
    #pragma unroll
    for (int i = 0; i < 4; ++i) { bsq[i] = FLT_MAX; bidx[i] = 0; }

    for (int cc = 0; cc < CODES; cc += TC) {
        float acc[4][4];
        #pragma unroll
        for (int i = 0; i < 4; ++i)
            #pragma unroll
            for (int j = 0; j < 4; ++j) acc[i][j] = 0.f;

        for (int kc = 0; kc < DIM; kc += KB) {
            __syncthreads();   // protect previous iteration's reads
            #pragma unroll
            for (int p = 0; p < 2; ++p) {
                int idx = tid + p * 256;       // 0..511
                int tok = idx & 63;
                int k4  = idx >> 6;            // 0..7
                float4 v = *reinterpret_cast<const float4*>(
                    x + (size_t)(n0 + tok) * DIM + kc + k4 * 4);
                xt[k4 * 4 + 0][tok] = v.x;
                xt[k4 * 4 + 1][tok] = v.y;
                xt[k4 * 4 + 2][tok] = v.z;
                xt[k4 * 4 + 3][tok] = v.w;
                float4 w = *reinterpret_cast<const float4*>(
                    embed + (size_t)(cc + tok) * DIM + kc + k4 * 4);
                et[k4 * 4 + 0][tok] = w.x;
                et[k4 * 4 + 1][tok] = w.y;
                et[k4 * 4 + 2][tok] = w.z;
                et[k4 * 4 + 3][tok] = w.w;
            }
            __syncthreads();
            #pragma unroll
            for (int k = 0; k < KB; ++k) {
                float4 a = *reinterpret_cast<const float4*>(&xt[k][ty * 4]);
                float4 b = *reinterpret_cast<const float4*>(&et[k][tx * 4]);
                acc[0][0] += a.x * b.x; acc[0][1] += a.x * b.y; acc[0][2] += a.x * b.z; acc[0][3] += a.x * b.w;
                acc[1][0] += a.y * b.x; acc[1][1] += a.y * b.y; acc[1][2] += a.y * b.z; acc[1][3] += a.y * b.w;
                acc[2][0] += a.z * b.x; acc[2][1] += a.z * b.y; acc[2][2] += a.z * b.z; acc[2][3] += a.z * b.w;
                acc[3][0] += a.w * b.x; acc[3][1] += a.w * b.y; acc[3][2] += a.w * b.z; acc[3][3] += a.w * b.w;
            }
        }

        float e2v[4];
        #pragma unroll
        for (int j = 0; j < 4; ++j) e2v[j] = e2[cc + tx * 4 + j];

        #pragma unroll
        for (int i = 0; i < 4; ++i) {
            float4 dv;
            #pragma unroll
            for (int j = 0; j < 4; ++j) {
                float sq = myx2[i] + e2v[j] - 2.0f * acc[i][j];
                sq = fmaxf(sq, 0.0f);
                float d = -sqrtf(sq);
                if (j == 0) dv.x = d; else if (j == 1) dv.y = d; else if (j == 2) dv.z = d; else dv.w = d;
                int code = cc + tx * 4 + j;
                if (sq < bsq[i]) { bsq[i] = sq; bidx[i] = code; }  // strict <: first-occurrence wins
            }
            *reinterpret_cast<float4*>(dist + (size_t)(n0 + ty * 4 + i) * CODES + cc + tx * 4) = dv;
        }
    }

    // reduce argmin across the 16 tx lanes (contiguous lanes ty*16..ty*16+15 in-wave)
    #pragma unroll
    for (int i = 0; i < 4; ++i) {
        float s = bsq[i];
        int   b = bidx[i];
        #pragma unroll
        for (int m = 8; m >= 1; m >>= 1) {
            float so = __shfl_xor(s, m);
            int   bo = __shfl_xor(b, m);
            if (so < s || (so == s && bo < b)) { s = so; b = bo; }
        }
        if (tx == 0) {
            int n = n0 + ty * 4 + i;
            ind_f[n] = (float)b;
            ind_i[n] = b;
        }
    }
}

// ---------------- gather quantize + scatter bins/embed_sum -------------------
__global__ void k_gs(const float* __restrict__ x, const float* __restrict__ embed,
                     const int* __restrict__ ind_i, float* __restrict__ q,
                     float* __restrict__ bins, float* __restrict__ esum) {
    int gid  = blockIdx.x * blockDim.x + threadIdx.x;
    int w    = gid >> 6;            // token
    int lane = threadIdx.x & 63;
    if (w >= N_TOK) return;
    int c = ind_i[w];
    float4 e4 = reinterpret_cast<const float4*>(embed + (size_t)c * DIM)[lane];
    float4 x4 = reinterpret_cast<const float4*>(x + (size_t)w * DIM)[lane];
    reinterpret_cast<float4*>(q + (size_t)w * DIM)[lane] = e4;
    float* ep = esum + (size_t)c * DIM + lane * 4;
    atomicAdd(ep + 0, x4.x);
    atomicAdd(ep + 1, x4.y);
    atomicAdd(ep + 2, x4.z);
    atomicAdd(ep + 3, x4.w);
    if (lane == 0) atomicAdd(bins + c, 1.0f);
}

// ---------------- finalize 1: new_cluster_size, total, smoothed --------------
__global__ void k_fin1(const float* __restrict__ cs, const float* __restrict__ bins,
                       float* __restrict__ out_ncs, float* __restrict__ smoothed) {
    __shared__ float red[256];
    __shared__ float s_total;
    int t = threadIdx.x;
    float ncs8[8];
    float partial = 0.f;
    #pragma unroll
    for (int r = 0; r < 8; ++r) {
        int c = t * 8 + r;
        float v = cs[c] * DECAY + bins[c] * (1.0f - DECAY);
        out_ncs[c] = v;
        ncs8[r] = v;
        partial += v;
    }
    red[t] = partial;
    __syncthreads();
    for (int s = 128; s >= 1; s >>= 1) {
        if (t < s) red[t] += red[t + s];
        __syncthreads();
    }
    if (t == 0) s_total = red[0];
    __syncthreads();
    float total = s_total;
    float denom = total + (float)CODES * EPSV;
    #pragma unroll
    for (int r = 0; r < 8; ++r) {
        int c = t * 8 + r;
        smoothed[c] = (ncs8[r] + EPSV) / denom * total;
    }
}

// ---------------- finalize 2: new_embed_avg, new_embed -----------------------
__global__ void k_fin2(const float* __restrict__ ea, const float* __restrict__ esum,
                       const float* __restrict__ smoothed,
                       float* __restrict__ out_nea, float* __restrict__ out_nemb) {
    int idx = blockIdx.x * blockDim.x + threadIdx.x;   // 0..524287
    int c = idx >> 8;
    float na = ea[idx] * DECAY + esum[idx] * (1.0f - DECAY);
    out_nea[idx] = na;
    out_nemb[idx] = na / smoothed[c];
}

extern "C" void kernel_launch(void* const* d_in, const int* in_sizes, int n_in,
                              void* d_out, int out_size, void* d_ws, size_t ws_size,
                              hipStream_t stream) {
    const float* x     = (const float*)d_in[0];
    const float* embed = (const float*)d_in[1];
    const float* eavg  = (const float*)d_in[2];
    const float* csz   = (const float*)d_in[3];
    float* out = (float*)d_out;
    float* ws  = (float*)d_ws;

    float* e2    = ws + WS_E2;
    float* x2    = ws + WS_X2;
    float* bins  = ws + WS_BINS;
    float* esum  = ws + WS_ESUM;
    float* smoo  = ws + WS_SMOO;
    int*   ind_i = (int*)(ws + WS_INDI);

    // zero bins + embed_sum (contiguous region)
    hipMemsetAsync(bins, 0, (size_t)(WS_SMOO - WS_BINS) * sizeof(float), stream);

    // e2, x2
    k_rowsq<<<(CODES * 64 + 255) / 256, 256, 0, stream>>>(embed, e2, CODES);
    k_rowsq<<<(N_TOK * 64 + 255) / 256, 256, 0, stream>>>(x, x2, N_TOK);

    // dist + argmin
    k_main<<<N_TOK / TN, 256, 0, stream>>>(x, embed, x2, e2,
                                           out + OUT_DIST, out + OUT_IND, ind_i);

    // quantize gather + EMA scatter
    k_gs<<<(N_TOK * 64 + 255) / 256, 256, 0, stream>>>(x, embed, ind_i,
                                                       out + OUT_Q, bins, esum);

    // EMA finalize
    k_fin1<<<1, 256, 0, stream>>>(csz, bins, out + OUT_NCS, smoo);
    k_fin2<<<(CODES * DIM) / 256, 256, 0, stream>>>(eavg, esum, smoo,
                                                    out + OUT_NEA, out + OUT_NEMB);
}

// Round 3
// 1034.331 us; speedup vs baseline: 1.4643x; 1.4643x over previous
//
#include <hip/hip_runtime.h>
#include <float.h>
#include <stdint.h>

// Problem constants (h=1, b=32, n=2048, d=256, c=2048)
#define N_TOK 65536
#define DIM   256
#define CODES 2048
#define DECAY 0.8f
#define EPSV  1e-5f

// Output offsets (floats) in d_out, concatenated in reference return order
#define OUT_Q    ((size_t)0)            // quantize: 16777216
#define OUT_IND  ((size_t)16777216)     // embed_ind: 65536 (written as float)
#define OUT_DIST ((size_t)16842752)     // dist: 134217728
#define OUT_NEMB ((size_t)151060480)    // new_embed: 524288
#define OUT_NCS  ((size_t)151584768)    // new_cluster_size: 2048
#define OUT_NEA  ((size_t)151586816)    // new_embed_avg: 524288

// Workspace layout (bytes)
#define WSB_KEYS ((size_t)0)         // u64[65536] = 524288  (memset 0xFF)
#define WSB_BINS ((size_t)524288)    // f32[2048]  = 8192    (memset 0)
#define WSB_ESUM ((size_t)532480)    // f32[524288]= 2097152 (memset 0)
#define WSB_EHI  ((size_t)2629632)   // ushort[524288] = 1048576
#define WSB_ELO  ((size_t)3678208)   // ushort[524288] = 1048576
#define WSB_X2   ((size_t)4726784)   // f32[65536] = 262144
#define WSB_E2   ((size_t)4988928)   // f32[2048]  = 8192
#define WSB_SMOO ((size_t)4997120)   // f32[2048]  = 8192

typedef __attribute__((ext_vector_type(8))) short bf16x8;
typedef __attribute__((ext_vector_type(4))) float f32x4;

#define MFMA(a, b, c) __builtin_amdgcn_mfma_f32_16x16x32_bf16(a, b, c, 0, 0, 0)

typedef const unsigned int __attribute__((address_space(1)))* as1_u32p;
typedef unsigned int __attribute__((address_space(3)))* as3_u32p;

__device__ __forceinline__ void async_copy16(const void* g, void* l) {
    __builtin_amdgcn_global_load_lds((as1_u32p)g, (as3_u32p)l, 16, 0, 0);
}

__device__ __forceinline__ unsigned short f2bf(float f) {
    unsigned u = __float_as_uint(f);
    unsigned r = (u + 0x7FFFu + ((u >> 16) & 1u)) >> 16;   // RN-even
    return (unsigned short)r;
}
__device__ __forceinline__ float bf2f(unsigned short s) {
    return __uint_as_float(((unsigned)s) << 16);
}

// ---------------- split f32 -> bf16 hi/lo + row sum-of-squares ----------------
// one wave per 256-elem row; lane handles 4 consecutive floats
__global__ void k_split(const float* __restrict__ in, unsigned short* __restrict__ hi,
                        unsigned short* __restrict__ lo, float* __restrict__ sq, int rows) {
    int gid = blockIdx.x * blockDim.x + threadIdx.x;
    int r = gid >> 6;
    int l = threadIdx.x & 63;
    if (r >= rows) return;
    float4 v = reinterpret_cast<const float4*>(in + (size_t)r * DIM)[l];
    ushort4 h, w;
    h.x = f2bf(v.x); h.y = f2bf(v.y); h.z = f2bf(v.z); h.w = f2bf(v.w);
    w.x = f2bf(v.x - bf2f(h.x));
    w.y = f2bf(v.y - bf2f(h.y));
    w.z = f2bf(v.z - bf2f(h.z));
    w.w = f2bf(v.w - bf2f(h.w));
    reinterpret_cast<ushort4*>(hi + (size_t)r * DIM)[l] = h;
    reinterpret_cast<ushort4*>(lo + (size_t)r * DIM)[l] = w;
    float s = v.x * v.x + v.y * v.y + v.z * v.z + v.w * v.w;
    #pragma unroll
    for (int m = 32; m >= 1; m >>= 1) s += __shfl_xor(s, m);
    if (l == 0) sq[r] = s;
}

// ---------------- main: 4-pass split-bf16 MFMA GEMM + dist + argmin ----------
// 128x128 tile, 256 threads = 4 waves (2x2 of 64x64), BK=32, K=256 (8 steps).
__launch_bounds__(256)
__global__ void k_main(const unsigned short* __restrict__ xhi, const unsigned short* __restrict__ xlo,
                       const unsigned short* __restrict__ ehi, const unsigned short* __restrict__ elo,
                       const float* __restrict__ x2, const float* __restrict__ e2,
                       float* __restrict__ dist, unsigned long long* __restrict__ keys) {
    __shared__ unsigned short lds[4][128][32];   // Ahi, Alo, Bhi, Blo tiles (8 KB each)
    const int tid = threadIdx.x;
    const int l   = tid & 63;
    const int wid = tid >> 6;
    const int wm  = wid >> 1, wn = wid & 1;
    const int t0  = blockIdx.y * 128;
    const int c0  = blockIdx.x * 128;

    // this wave stages tile `wid`
    const unsigned short* gsrc = (wid == 0) ? xhi : (wid == 1) ? xlo : (wid == 2) ? ehi : elo;
    const int r0 = (wid < 2) ? t0 : c0;

    f32x4 acc[4][4];
    #pragma unroll
    for (int i = 0; i < 4; ++i)
        #pragma unroll
        for (int j = 0; j < 4; ++j) acc[i][j] = (f32x4){0.f, 0.f, 0.f, 0.f};

    const int kg = l >> 4;     // k-group 0..3
    const int lr = l & 15;

    for (int kc = 0; kc < DIM; kc += 32) {
        // stage this wave's 128x32 bf16 tile: 8 x (64 lanes x 16B)
        const unsigned short* g = gsrc + (size_t)(r0 + (l >> 2)) * DIM + kc + (l & 3) * 8;
        unsigned short* lbase = &lds[wid][0][0];
        #pragma unroll
        for (int i = 0; i < 8; ++i)
            async_copy16(g + (size_t)i * 16 * DIM, lbase + i * 512);
        __syncthreads();   // drains vmcnt: tiles visible to all waves

        bf16x8 ah[4], al[4], bh[4], bl[4];
        #pragma unroll
        for (int f = 0; f < 4; ++f) {
            ah[f] = *(const bf16x8*)&lds[0][wm * 64 + f * 16 + lr][kg * 8];
            al[f] = *(const bf16x8*)&lds[1][wm * 64 + f * 16 + lr][kg * 8];
            bh[f] = *(const bf16x8*)&lds[2][wn * 64 + f * 16 + lr][kg * 8];
            bl[f] = *(const bf16x8*)&lds[3][wn * 64 + f * 16 + lr][kg * 8];
        }
        #pragma unroll
        for (int mf = 0; mf < 4; ++mf)
            #pragma unroll
            for (int nf = 0; nf < 4; ++nf) {
                acc[mf][nf] = MFMA(al[mf], bl[nf], acc[mf][nf]);  // smallest first
                acc[mf][nf] = MFMA(al[mf], bh[nf], acc[mf][nf]);
                acc[mf][nf] = MFMA(ah[mf], bl[nf], acc[mf][nf]);
                acc[mf][nf] = MFMA(ah[mf], bh[nf], acc[mf][nf]);
            }
        __syncthreads();   // all waves done reading before next stage overwrites
    }

    // epilogue: sq = x2 + e2 - 2*xy; dist = -sqrt(max(sq,0)); argmin via packed atomicMin
    float e2v[4];
    #pragma unroll
    for (int nf = 0; nf < 4; ++nf) e2v[nf] = e2[c0 + wn * 64 + nf * 16 + lr];

    #pragma unroll
    for (int mf = 0; mf < 4; ++mf) {
        #pragma unroll
        for (int reg = 0; reg < 4; ++reg) {
            int t = t0 + wm * 64 + mf * 16 + kg * 4 + reg;     // D row = (lane>>4)*4 + reg
            float tx2 = x2[t];
            float bs = FLT_MAX;
            int   bc = 0;
            #pragma unroll
            for (int nf = 0; nf < 4; ++nf) {
                int c = c0 + wn * 64 + nf * 16 + lr;           // D col = lane&15
                float sq = fmaxf(tx2 + e2v[nf] - 2.0f * acc[mf][nf][reg], 0.0f);
                __builtin_nontemporal_store(-sqrtf(sq), dist + (size_t)t * CODES + c);
                if (sq < bs) { bs = sq; bc = c; }
            }
            // reduce across the 16 lanes of this row-group (contiguous, xor stays in-group)
            #pragma unroll
            for (int m = 8; m >= 1; m >>= 1) {
                float os = __shfl_xor(bs, m);
                int   oc = __shfl_xor(bc, m);
                if (os < bs || (os == bs && oc < bc)) { bs = os; bc = oc; }
            }
            if (lr == 0) {
                unsigned long long key = ((unsigned long long)__float_as_uint(bs) << 32) | (unsigned)bc;
                atomicMin(keys + t, key);
            }
        }
    }
}

// ---------------- gather quantize + scatter bins/embed_sum + ind -------------
__global__ void k_gs(const float* __restrict__ x, const float* __restrict__ embed,
                     const unsigned long long* __restrict__ keys, float* __restrict__ q,
                     float* __restrict__ ind_f, float* __restrict__ bins, float* __restrict__ esum) {
    int gid  = blockIdx.x * blockDim.x + threadIdx.x;
    int w    = gid >> 6;            // token
    int lane = threadIdx.x & 63;
    if (w >= N_TOK) return;
    int c = (int)(keys[w] & 0xFFFFFFFFULL);
    f32x4 e4 = reinterpret_cast<const f32x4*>(embed + (size_t)c * DIM)[lane];
    float4 x4 = reinterpret_cast<const float4*>(x + (size_t)w * DIM)[lane];
    __builtin_nontemporal_store(e4, reinterpret_cast<f32x4*>(q + (size_t)w * DIM) + lane);
    float* ep = esum + (size_t)c * DIM + lane * 4;
    atomicAdd(ep + 0, x4.x);
    atomicAdd(ep + 1, x4.y);
    atomicAdd(ep + 2, x4.z);
    atomicAdd(ep + 3, x4.w);
    if (lane == 0) {
        ind_f[w] = (float)c;
        atomicAdd(bins + c, 1.0f);
    }
}

// ---------------- finalize 1: new_cluster_size, total, smoothed --------------
__global__ void k_fin1(const float* __restrict__ cs, const float* __restrict__ bins,
                       float* __restrict__ out_ncs, float* __restrict__ smoothed) {
    __shared__ float red[256];
    __shared__ float s_total;
    int t = threadIdx.x;
    float ncs8[8];
    float partial = 0.f;
    #pragma unroll
    for (int r = 0; r < 8; ++r) {
        int c = t * 8 + r;
        float v = cs[c] * DECAY + bins[c] * (1.0f - DECAY);
        out_ncs[c] = v;
        ncs8[r] = v;
        partial += v;
    }
    red[t] = partial;
    __syncthreads();
    for (int s = 128; s >= 1; s >>= 1) {
        if (t < s) red[t] += red[t + s];
        __syncthreads();
    }
    if (t == 0) s_total = red[0];
    __syncthreads();
    float total = s_total;
    float denom = total + (float)CODES * EPSV;
    #pragma unroll
    for (int r = 0; r < 8; ++r) {
        int c = t * 8 + r;
        smoothed[c] = (ncs8[r] + EPSV) / denom * total;
    }
}

// ---------------- finalize 2: new_embed_avg, new_embed -----------------------
__global__ void k_fin2(const float* __restrict__ ea, const float* __restrict__ esum,
                       const float* __restrict__ smoothed,
                       float* __restrict__ out_nea, float* __restrict__ out_nemb) {
    int idx = blockIdx.x * blockDim.x + threadIdx.x;   // 0..524287
    int c = idx >> 8;
    float na = ea[idx] * DECAY + esum[idx] * (1.0f - DECAY);
    out_nea[idx] = na;
    out_nemb[idx] = na / smoothed[c];
}

extern "C" void kernel_launch(void* const* d_in, const int* in_sizes, int n_in,
                              void* d_out, int out_size, void* d_ws, size_t ws_size,
                              hipStream_t stream) {
    const float* x     = (const float*)d_in[0];
    const float* embed = (const float*)d_in[1];
    const float* eavg  = (const float*)d_in[2];
    const float* csz   = (const float*)d_in[3];
    float* out = (float*)d_out;
    char*  wsb = (char*)d_ws;

    unsigned long long* keys = (unsigned long long*)(wsb + WSB_KEYS);
    float*          bins = (float*)(wsb + WSB_BINS);
    float*          esum = (float*)(wsb + WSB_ESUM);
    unsigned short* ehi  = (unsigned short*)(wsb + WSB_EHI);
    unsigned short* elo  = (unsigned short*)(wsb + WSB_ELO);
    float*          x2   = (float*)(wsb + WSB_X2);
    float*          e2   = (float*)(wsb + WSB_E2);
    float*          smoo = (float*)(wsb + WSB_SMOO);

    // x hi/lo staged in the quantize output region (exactly the same byte size);
    // k_gs overwrites it AFTER k_main has consumed it (stream-ordered).
    unsigned short* xhi = (unsigned short*)(out + OUT_Q);
    unsigned short* xlo = xhi + (size_t)N_TOK * DIM;

    (void)hipMemsetAsync(wsb + WSB_KEYS, 0xFF, 524288, stream);           // keys = +inf
    (void)hipMemsetAsync(wsb + WSB_BINS, 0, 8192 + 2097152, stream);      // bins + esum = 0

    k_split<<<N_TOK * 64 / 256, 256, 0, stream>>>(x, xhi, xlo, x2, N_TOK);
    k_split<<<CODES * 64 / 256, 256, 0, stream>>>(embed, ehi, elo, e2, CODES);

    k_main<<<dim3(CODES / 128, N_TOK / 128), 256, 0, stream>>>(
        xhi, xlo, ehi, elo, x2, e2, out + OUT_DIST, keys);

    k_gs<<<N_TOK * 64 / 256, 256, 0, stream>>>(x, embed, keys,
                                               out + OUT_Q, out + OUT_IND, bins, esum);

    k_fin1<<<1, 256, 0, stream>>>(csz, bins, out + OUT_NCS, smoo);
    k_fin2<<<(CODES * DIM) / 256, 256, 0, stream>>>(eavg, esum, smoo,
                                                    out + OUT_NEA, out + OUT_NEMB);
}

// Round 4
// 890.513 us; speedup vs baseline: 1.7008x; 1.1615x over previous
//
#include <hip/hip_runtime.h>
#include <float.h>
#include <stdint.h>

// Problem constants (h=1, b=32, n=2048, d=256, c=2048)
#define N_TOK 65536
#define DIM   256
#define CODES 2048
#define DECAY 0.8f
#define EPSV  1e-5f

// Output offsets (floats) in d_out, concatenated in reference return order
#define OUT_Q    ((size_t)0)            // quantize: 16777216
#define OUT_IND  ((size_t)16777216)     // embed_ind: 65536 (written as float)
#define OUT_DIST ((size_t)16842752)     // dist: 134217728
#define OUT_NEMB ((size_t)151060480)    // new_embed: 524288
#define OUT_NCS  ((size_t)151584768)    // new_cluster_size: 2048
#define OUT_NEA  ((size_t)151586816)    // new_embed_avg: 524288

// Workspace layout (bytes)
#define WSB_KEYS ((size_t)0)         // u64[65536] = 524288 (memset 0xFF)
#define WSB_CNT  ((size_t)524288)    // int[2048] = 8192   (memset 0)
#define WSB_CUR  ((size_t)532480)    // int[2048] = 8192   (memset 0)
#define WSB_OFF  ((size_t)540672)    // int[2048] = 8192
#define WSB_LIST ((size_t)548864)    // int[65536] = 262144
#define WSB_EHI  ((size_t)811008)    // ushort[524288] = 1048576
#define WSB_ELO  ((size_t)1859584)   // ushort[524288] = 1048576
#define WSB_X2   ((size_t)2908160)   // f32[65536] = 262144
#define WSB_E2   ((size_t)3170304)   // f32[2048] = 8192
#define WSB_SMOO ((size_t)3178496)   // f32[2048] = 8192

typedef __attribute__((ext_vector_type(8))) short bf16x8;
typedef __attribute__((ext_vector_type(4))) float f32x4;

#define MFMA(a, b, c) __builtin_amdgcn_mfma_f32_16x16x32_bf16(a, b, c, 0, 0, 0)

typedef const unsigned int __attribute__((address_space(1)))* as1_u32p;
typedef unsigned int __attribute__((address_space(3)))* as3_u32p;

__device__ __forceinline__ void async_copy16(const void* g, void* l) {
    __builtin_amdgcn_global_load_lds((as1_u32p)g, (as3_u32p)l, 16, 0, 0);
}

__device__ __forceinline__ unsigned short f2bf(float f) {
    unsigned u = __float_as_uint(f);
    unsigned r = (u + 0x7FFFu + ((u >> 16) & 1u)) >> 16;   // RN-even
    return (unsigned short)r;
}
__device__ __forceinline__ float bf2f(unsigned short s) {
    return __uint_as_float(((unsigned)s) << 16);
}

// ---------------- split f32 -> bf16 hi/lo + row sum-of-squares ----------------
__global__ void k_split(const float* __restrict__ in, unsigned short* __restrict__ hi,
                        unsigned short* __restrict__ lo, float* __restrict__ sq, int rows) {
    int gid = blockIdx.x * blockDim.x + threadIdx.x;
    int r = gid >> 6;
    int l = threadIdx.x & 63;
    if (r >= rows) return;
    float4 v = reinterpret_cast<const float4*>(in + (size_t)r * DIM)[l];
    ushort4 h, w;
    h.x = f2bf(v.x); h.y = f2bf(v.y); h.z = f2bf(v.z); h.w = f2bf(v.w);
    w.x = f2bf(v.x - bf2f(h.x));
    w.y = f2bf(v.y - bf2f(h.y));
    w.z = f2bf(v.z - bf2f(h.z));
    w.w = f2bf(v.w - bf2f(h.w));
    reinterpret_cast<ushort4*>(hi + (size_t)r * DIM)[l] = h;
    reinterpret_cast<ushort4*>(lo + (size_t)r * DIM)[l] = w;
    float s = v.x * v.x + v.y * v.y + v.z * v.z + v.w * v.w;
    #pragma unroll
    for (int m = 32; m >= 1; m >>= 1) s += __shfl_xor(s, m);
    if (l == 0) sq[r] = s;
}

// ---------------- main: 4-pass split-bf16 MFMA GEMM + dist + argmin ----------
__launch_bounds__(256)
__global__ void k_main(const unsigned short* __restrict__ xhi, const unsigned short* __restrict__ xlo,
                       const unsigned short* __restrict__ ehi, const unsigned short* __restrict__ elo,
                       const float* __restrict__ x2, const float* __restrict__ e2,
                       float* __restrict__ dist, unsigned long long* __restrict__ keys) {
    __shared__ unsigned short lds[4][128][32];   // Ahi, Alo, Bhi, Blo tiles (8 KB each)
    const int tid = threadIdx.x;
    const int l   = tid & 63;
    const int wid = tid >> 6;
    const int wm  = wid >> 1, wn = wid & 1;
    const int t0  = blockIdx.y * 128;
    const int c0  = blockIdx.x * 128;

    const unsigned short* gsrc = (wid == 0) ? xhi : (wid == 1) ? xlo : (wid == 2) ? ehi : elo;
    const int r0 = (wid < 2) ? t0 : c0;

    f32x4 acc[4][4];
    #pragma unroll
    for (int i = 0; i < 4; ++i)
        #pragma unroll
        for (int j = 0; j < 4; ++j) acc[i][j] = (f32x4){0.f, 0.f, 0.f, 0.f};

    const int kg = l >> 4;     // k-group 0..3
    const int lr = l & 15;

    for (int kc = 0; kc < DIM; kc += 32) {
        const unsigned short* g = gsrc + (size_t)(r0 + (l >> 2)) * DIM + kc + (l & 3) * 8;
        unsigned short* lbase = &lds[wid][0][0];
        #pragma unroll
        for (int i = 0; i < 8; ++i)
            async_copy16(g + (size_t)i * 16 * DIM, lbase + i * 512);
        __syncthreads();

        bf16x8 ah[4], al[4], bh[4], bl[4];
        #pragma unroll
        for (int f = 0; f < 4; ++f) {
            ah[f] = *(const bf16x8*)&lds[0][wm * 64 + f * 16 + lr][kg * 8];
            al[f] = *(const bf16x8*)&lds[1][wm * 64 + f * 16 + lr][kg * 8];
            bh[f] = *(const bf16x8*)&lds[2][wn * 64 + f * 16 + lr][kg * 8];
            bl[f] = *(const bf16x8*)&lds[3][wn * 64 + f * 16 + lr][kg * 8];
        }
        #pragma unroll
        for (int mf = 0; mf < 4; ++mf)
            #pragma unroll
            for (int nf = 0; nf < 4; ++nf) {
                acc[mf][nf] = MFMA(al[mf], bl[nf], acc[mf][nf]);
                acc[mf][nf] = MFMA(al[mf], bh[nf], acc[mf][nf]);
                acc[mf][nf] = MFMA(ah[mf], bl[nf], acc[mf][nf]);
                acc[mf][nf] = MFMA(ah[mf], bh[nf], acc[mf][nf]);
            }
        __syncthreads();
    }

    float e2v[4];
    #pragma unroll
    for (int nf = 0; nf < 4; ++nf) e2v[nf] = e2[c0 + wn * 64 + nf * 16 + lr];

    #pragma unroll
    for (int mf = 0; mf < 4; ++mf) {
        #pragma unroll
        for (int reg = 0; reg < 4; ++reg) {
            int t = t0 + wm * 64 + mf * 16 + kg * 4 + reg;     // D row = (lane>>4)*4 + reg
            float tx2 = x2[t];
            float bs = FLT_MAX;
            int   bc = 0;
            #pragma unroll
            for (int nf = 0; nf < 4; ++nf) {
                int c = c0 + wn * 64 + nf * 16 + lr;           // D col = lane&15
                float sq = fmaxf(tx2 + e2v[nf] - 2.0f * acc[mf][nf][reg], 0.0f);
                __builtin_nontemporal_store(-sqrtf(sq), dist + (size_t)t * CODES + c);
                if (sq < bs) { bs = sq; bc = c; }
            }
            #pragma unroll
            for (int m = 8; m >= 1; m >>= 1) {
                float os = __shfl_xor(bs, m);
                int   oc = __shfl_xor(bc, m);
                if (os < bs || (os == bs && oc < bc)) { bs = os; bc = oc; }
            }
            if (lr == 0) {
                unsigned long long key = ((unsigned long long)__float_as_uint(bs) << 32) | (unsigned)bc;
                atomicMin(keys + t, key);
            }
        }
    }
}

// ---------------- count tokens per code + write ind --------------------------
__global__ void k_count(const unsigned long long* __restrict__ keys,
                        float* __restrict__ ind_f, int* __restrict__ cnt) {
    int t = blockIdx.x * blockDim.x + threadIdx.x;
    if (t >= N_TOK) return;
    int c = (int)(keys[t] & 0xFFFFFFFFULL);
    ind_f[t] = (float)c;
    atomicAdd(cnt + c, 1);
}

// ---------------- scan: offsets + new_cluster_size + smoothed (fused fin1) ---
__global__ void k_scan(const int* __restrict__ cnt, const float* __restrict__ cs,
                       int* __restrict__ offsets, float* __restrict__ out_ncs,
                       float* __restrict__ smoothed) {
    __shared__ int red[256];
    __shared__ float fred[256];
    __shared__ float s_total;
    int t = threadIdx.x;
    int c8[8];
    int own = 0;
    float ncs8[8];
    float fpart = 0.f;
    #pragma unroll
    for (int r = 0; r < 8; ++r) {
        int c = t * 8 + r;
        int v = cnt[c];
        c8[r] = v;
        own += v;
        float n = cs[c] * DECAY + (float)v * (1.0f - DECAY);
        out_ncs[c] = n;
        ncs8[r] = n;
        fpart += n;
    }
    red[t] = own;
    fred[t] = fpart;
    __syncthreads();
    // inclusive Hillis-Steele scan of int counts; tree-reduce float total
    for (int d = 1; d < 256; d <<= 1) {
        int v = (t >= d) ? red[t - d] : 0;
        __syncthreads();
        red[t] += v;
        __syncthreads();
    }
    for (int s = 128; s >= 1; s >>= 1) {
        if (t < s) fred[t] += fred[t + s];
        __syncthreads();
    }
    if (t == 0) s_total = fred[0];
    __syncthreads();
    int base = red[t] - own;   // exclusive prefix for this thread's first code
    float total = s_total;
    float denom = total + (float)CODES * EPSV;
    #pragma unroll
    for (int r = 0; r < 8; ++r) {
        int c = t * 8 + r;
        offsets[c] = base;
        base += c8[r];
        smoothed[c] = (ncs8[r] + EPSV) / denom * total;
    }
}

// ---------------- scatter token ids into per-code buckets --------------------
__global__ void k_scatter(const unsigned long long* __restrict__ keys,
                          const int* __restrict__ offsets, int* __restrict__ cursor,
                          int* __restrict__ list) {
    int t = blockIdx.x * blockDim.x + threadIdx.x;
    if (t >= N_TOK) return;
    int c = (int)(keys[t] & 0xFFFFFFFFULL);
    int pos = atomicAdd(cursor + c, 1);
    list[offsets[c] + pos] = t;
}

// ---------------- quantize gather: q[t] = embed[c] ---------------------------
__global__ void k_q(const float* __restrict__ embed, const unsigned long long* __restrict__ keys,
                    float* __restrict__ q) {
    int gid  = blockIdx.x * blockDim.x + threadIdx.x;
    int w    = gid >> 6;            // token
    int lane = threadIdx.x & 63;
    if (w >= N_TOK) return;
    int c = (int)(keys[w] & 0xFFFFFFFFULL);
    f32x4 e4 = reinterpret_cast<const f32x4*>(embed + (size_t)c * DIM)[lane];
    __builtin_nontemporal_store(e4, reinterpret_cast<f32x4*>(q + (size_t)w * DIM) + lane);
}

// ---------------- per-code sum of x rows + fused fin2 ------------------------
// one block (4 waves) per code; wave w sums tokens w, w+4, ...; LDS-combine.
__global__ void k_esum(const float* __restrict__ x, const int* __restrict__ cnt,
                       const int* __restrict__ offsets, const int* __restrict__ list,
                       const float* __restrict__ ea, const float* __restrict__ smoothed,
                       float* __restrict__ out_nea, float* __restrict__ out_nemb) {
    __shared__ f32x4 part[4][64];
    int c    = blockIdx.x;
    int tid  = threadIdx.x;
    int w    = tid >> 6;
    int lane = tid & 63;
    int n    = cnt[c];
    int off  = offsets[c];
    f32x4 s = (f32x4){0.f, 0.f, 0.f, 0.f};
    for (int i = w; i < n; i += 4) {
        int t = list[off + i];
        s += reinterpret_cast<const f32x4*>(x + (size_t)t * DIM)[lane];
    }
    part[w][lane] = s;
    __syncthreads();
    if (w == 0) {
        f32x4 tot = part[0][lane] + part[1][lane] + part[2][lane] + part[3][lane];
        size_t idx = (size_t)c * DIM + lane * 4;
        f32x4 ea4 = *reinterpret_cast<const f32x4*>(ea + idx);
        f32x4 nea;
        float inv = 1.0f / smoothed[c];
        #pragma unroll
        for (int j = 0; j < 4; ++j) nea[j] = ea4[j] * DECAY + tot[j] * (1.0f - DECAY);
        *reinterpret_cast<f32x4*>(out_nea + idx) = nea;
        f32x4 nemb;
        #pragma unroll
        for (int j = 0; j < 4; ++j) nemb[j] = nea[j] * inv;
        *reinterpret_cast<f32x4*>(out_nemb + idx) = nemb;
    }
}

extern "C" void kernel_launch(void* const* d_in, const int* in_sizes, int n_in,
                              void* d_out, int out_size, void* d_ws, size_t ws_size,
                              hipStream_t stream) {
    const float* x     = (const float*)d_in[0];
    const float* embed = (const float*)d_in[1];
    const float* eavg  = (const float*)d_in[2];
    const float* csz   = (const float*)d_in[3];
    float* out = (float*)d_out;
    char*  wsb = (char*)d_ws;

    unsigned long long* keys = (unsigned long long*)(wsb + WSB_KEYS);
    int*            cnt  = (int*)(wsb + WSB_CNT);
    int*            cur  = (int*)(wsb + WSB_CUR);
    int*            off  = (int*)(wsb + WSB_OFF);
    int*            list = (int*)(wsb + WSB_LIST);
    unsigned short* ehi  = (unsigned short*)(wsb + WSB_EHI);
    unsigned short* elo  = (unsigned short*)(wsb + WSB_ELO);
    float*          x2   = (float*)(wsb + WSB_X2);
    float*          e2   = (float*)(wsb + WSB_E2);
    float*          smoo = (float*)(wsb + WSB_SMOO);

    // x hi/lo staged in the quantize output region (same byte size); k_q
    // overwrites it AFTER k_main has consumed it (stream-ordered).
    unsigned short* xhi = (unsigned short*)(out + OUT_Q);
    unsigned short* xlo = xhi + (size_t)N_TOK * DIM;

    (void)hipMemsetAsync(wsb + WSB_KEYS, 0xFF, 524288, stream);       // keys = +inf
    (void)hipMemsetAsync(wsb + WSB_CNT, 0, 16384, stream);            // cnt + cursor = 0

    k_split<<<N_TOK * 64 / 256, 256, 0, stream>>>(x, xhi, xlo, x2, N_TOK);
    k_split<<<CODES * 64 / 256, 256, 0, stream>>>(embed, ehi, elo, e2, CODES);

    k_main<<<dim3(CODES / 128, N_TOK / 128), 256, 0, stream>>>(
        xhi, xlo, ehi, elo, x2, e2, out + OUT_DIST, keys);

    k_count<<<N_TOK / 256, 256, 0, stream>>>(keys, out + OUT_IND, cnt);
    k_scan<<<1, 256, 0, stream>>>(cnt, csz, off, out + OUT_NCS, smoo);
    k_scatter<<<N_TOK / 256, 256, 0, stream>>>(keys, off, cur, list);
    k_q<<<N_TOK * 64 / 256, 256, 0, stream>>>(embed, keys, out + OUT_Q);
    k_esum<<<CODES, 256, 0, stream>>>(x, cnt, off, list, eavg, smoo,
                                      out + OUT_NEA, out + OUT_NEMB);
}

// Round 5
// 715.404 us; speedup vs baseline: 2.1171x; 1.2448x over previous
//
#include <hip/hip_runtime.h>
#include <float.h>
#include <stdint.h>

// Problem constants (h=1, b=32, n=2048, d=256, c=2048)
#define N_TOK 65536
#define DIM   256
#define CODES 2048
#define DECAY 0.8f
#define EPSV  1e-5f

// Output offsets (floats) in d_out, concatenated in reference return order
#define OUT_Q    ((size_t)0)            // quantize: 16777216
#define OUT_IND  ((size_t)16777216)     // embed_ind: 65536 (written as float)
#define OUT_DIST ((size_t)16842752)     // dist: 134217728
#define OUT_NEMB ((size_t)151060480)    // new_embed: 524288
#define OUT_NCS  ((size_t)151584768)    // new_cluster_size: 2048
#define OUT_NEA  ((size_t)151586816)    // new_embed_avg: 524288

// Workspace layout (bytes)
#define WSB_KEYS ((size_t)0)         // u64[65536] = 524288 (memset 0xFF)
#define WSB_CNT  ((size_t)524288)    // int[2048] = 8192   (memset 0)
#define WSB_CUR  ((size_t)532480)    // int[2048] = 8192   (memset 0)
#define WSB_OFF  ((size_t)540672)    // int[2048] = 8192
#define WSB_LIST ((size_t)548864)    // int[65536] = 262144
#define WSB_EHI  ((size_t)811008)    // ushort[524288] = 1048576
#define WSB_ELO  ((size_t)1859584)   // ushort[524288] = 1048576
#define WSB_X2   ((size_t)2908160)   // f32[65536] = 262144
#define WSB_E2   ((size_t)3170304)   // f32[2048] = 8192
#define WSB_SMOO ((size_t)3178496)   // f32[2048] = 8192

typedef __attribute__((ext_vector_type(8))) short bf16x8;
typedef __attribute__((ext_vector_type(4))) float f32x4;

#define MFMA(a, b, c) __builtin_amdgcn_mfma_f32_16x16x32_bf16(a, b, c, 0, 0, 0)

typedef const unsigned int __attribute__((address_space(1)))* as1_u32p;
typedef unsigned int __attribute__((address_space(3)))* as3_u32p;

__device__ __forceinline__ void async_copy16(const void* g, void* l) {
    __builtin_amdgcn_global_load_lds((as1_u32p)g, (as3_u32p)l, 16, 0, 0);
}

__device__ __forceinline__ unsigned short f2bf(float f) {
    unsigned u = __float_as_uint(f);
    unsigned r = (u + 0x7FFFu + ((u >> 16) & 1u)) >> 16;   // RN-even
    return (unsigned short)r;
}
__device__ __forceinline__ float bf2f(unsigned short s) {
    return __uint_as_float(((unsigned)s) << 16);
}

// ---------------- split f32 -> bf16 hi/lo + row sum-of-squares ----------------
__global__ void k_split(const float* __restrict__ in, unsigned short* __restrict__ hi,
                        unsigned short* __restrict__ lo, float* __restrict__ sq, int rows) {
    int gid = blockIdx.x * blockDim.x + threadIdx.x;
    int r = gid >> 6;
    int l = threadIdx.x & 63;
    if (r >= rows) return;
    float4 v = reinterpret_cast<const float4*>(in + (size_t)r * DIM)[l];
    ushort4 h, w;
    h.x = f2bf(v.x); h.y = f2bf(v.y); h.z = f2bf(v.z); h.w = f2bf(v.w);
    w.x = f2bf(v.x - bf2f(h.x));
    w.y = f2bf(v.y - bf2f(h.y));
    w.z = f2bf(v.z - bf2f(h.z));
    w.w = f2bf(v.w - bf2f(h.w));
    reinterpret_cast<ushort4*>(hi + (size_t)r * DIM)[l] = h;
    reinterpret_cast<ushort4*>(lo + (size_t)r * DIM)[l] = w;
    float s = v.x * v.x + v.y * v.y + v.z * v.z + v.w * v.w;
    #pragma unroll
    for (int m = 32; m >= 1; m >>= 1) s += __shfl_xor(s, m);
    if (l == 0) sq[r] = s;
}

// ---------------- main: 4-pass split-bf16 MFMA GEMM + dist + argmin ----------
// 128x128 tile, 4 waves (2x2 of 64x64), BK=32, K=256 (8 steps).
// Double-buffered LDS; global-source chunk pre-swizzle <-> read-side slot XOR
// (rule #21: gload_lds dest stays linear).
__launch_bounds__(256)
__global__ void k_main(const unsigned short* __restrict__ xhi, const unsigned short* __restrict__ xlo,
                       const unsigned short* __restrict__ ehi, const unsigned short* __restrict__ elo,
                       const float* __restrict__ x2, const float* __restrict__ e2,
                       float* __restrict__ dist, unsigned long long* __restrict__ keys) {
    __shared__ unsigned short lds[2][4][128][32];   // dbuf x {Ahi,Alo,Bhi,Blo} x 8KB
    const int tid = threadIdx.x;
    const int l   = tid & 63;
    const int wid = tid >> 6;
    const int wm  = wid >> 1, wn = wid & 1;
    const int t0  = blockIdx.y * 128;
    const int c0  = blockIdx.x * 128;

    const unsigned short* gsrc = (wid == 0) ? xhi : (wid == 1) ? xlo : (wid == 2) ? ehi : elo;
    const int r0 = (wid < 2) ? t0 : c0;

    // staging pointer with chunk pre-swizzle: lane l stages LDS slot (l&3) of
    // row (l>>2)+16i; the data that must land there is global chunk
    // (l&3) ^ ((l>>3)&3)  (independent of i since 8i % 4 == 0).
    const int swc = ((l & 3) ^ ((l >> 3) & 3)) * 8;
    const unsigned short* gstage = gsrc + (size_t)(r0 + (l >> 2)) * DIM + swc;

    f32x4 acc[4][4];
    #pragma unroll
    for (int i = 0; i < 4; ++i)
        #pragma unroll
        for (int j = 0; j < 4; ++j) acc[i][j] = (f32x4){0.f, 0.f, 0.f, 0.f};

    const int kg = l >> 4;     // k-group 0..3
    const int lr = l & 15;
    const int ks = (kg ^ ((lr >> 1) & 3)) * 8;   // swizzled slot (shorts) for reads

    // prologue: stage K-step 0 into buf 0
    {
        unsigned short* lb = &lds[0][wid][0][0];
        #pragma unroll
        for (int i = 0; i < 8; ++i)
            async_copy16(gstage + (size_t)i * 16 * DIM, lb + i * 512);
    }
    __syncthreads();

    for (int step = 0; step < 8; ++step) {
        const int cur = step & 1;
        if (step < 7) {   // issue next-step staging first (overlaps ds_read+MFMA)
            const unsigned short* g = gstage + (size_t)(step + 1) * 32;
            unsigned short* lb = &lds[cur ^ 1][wid][0][0];
            #pragma unroll
            for (int i = 0; i < 8; ++i)
                async_copy16(g + (size_t)i * 16 * DIM, lb + i * 512);
        }

        bf16x8 ah[4], al[4], bh[4], bl[4];
        #pragma unroll
        for (int f = 0; f < 4; ++f) {
            ah[f] = *(const bf16x8*)&lds[cur][0][wm * 64 + f * 16 + lr][ks];
            al[f] = *(const bf16x8*)&lds[cur][1][wm * 64 + f * 16 + lr][ks];
            bh[f] = *(const bf16x8*)&lds[cur][2][wn * 64 + f * 16 + lr][ks];
            bl[f] = *(const bf16x8*)&lds[cur][3][wn * 64 + f * 16 + lr][ks];
        }
        __builtin_amdgcn_s_setprio(1);
        #pragma unroll
        for (int mf = 0; mf < 4; ++mf)
            #pragma unroll
            for (int nf = 0; nf < 4; ++nf) {
                acc[mf][nf] = MFMA(al[mf], bl[nf], acc[mf][nf]);
                acc[mf][nf] = MFMA(al[mf], bh[nf], acc[mf][nf]);
                acc[mf][nf] = MFMA(ah[mf], bl[nf], acc[mf][nf]);
                acc[mf][nf] = MFMA(ah[mf], bh[nf], acc[mf][nf]);
            }
        __builtin_amdgcn_s_setprio(0);
        __syncthreads();   // drains vmcnt (staging issued ~64 MFMAs ago) + barrier
    }

    float e2v[4];
    #pragma unroll
    for (int nf = 0; nf < 4; ++nf) e2v[nf] = e2[c0 + wn * 64 + nf * 16 + lr];

    #pragma unroll
    for (int mf = 0; mf < 4; ++mf) {
        #pragma unroll
        for (int reg = 0; reg < 4; ++reg) {
            int t = t0 + wm * 64 + mf * 16 + kg * 4 + reg;     // D row = (lane>>4)*4 + reg
            float tx2 = x2[t];
            float bs = FLT_MAX;
            int   bc = 0;
            #pragma unroll
            for (int nf = 0; nf < 4; ++nf) {
                int c = c0 + wn * 64 + nf * 16 + lr;           // D col = lane&15
                float sq = fmaxf(tx2 + e2v[nf] - 2.0f * acc[mf][nf][reg], 0.0f);
                __builtin_nontemporal_store(-sqrtf(sq), dist + (size_t)t * CODES + c);
                if (sq < bs) { bs = sq; bc = c; }
            }
            #pragma unroll
            for (int m = 8; m >= 1; m >>= 1) {
                float os = __shfl_xor(bs, m);
                int   oc = __shfl_xor(bc, m);
                if (os < bs || (os == bs && oc < bc)) { bs = os; bc = oc; }
            }
            if (lr == 0) {
                unsigned long long key = ((unsigned long long)__float_as_uint(bs) << 32) | (unsigned)bc;
                atomicMin(keys + t, key);
            }
        }
    }
}

// ---------------- count tokens per code + write ind --------------------------
__global__ void k_count(const unsigned long long* __restrict__ keys,
                        float* __restrict__ ind_f, int* __restrict__ cnt) {
    int t = blockIdx.x * blockDim.x + threadIdx.x;
    if (t >= N_TOK) return;
    int c = (int)(keys[t] & 0xFFFFFFFFULL);
    ind_f[t] = (float)c;
    atomicAdd(cnt + c, 1);
}

// ---------------- scan: offsets + new_cluster_size + smoothed (fused fin1) ---
__global__ void k_scan(const int* __restrict__ cnt, const float* __restrict__ cs,
                       int* __restrict__ offsets, float* __restrict__ out_ncs,
                       float* __restrict__ smoothed) {
    __shared__ int red[256];
    __shared__ float fred[256];
    __shared__ float s_total;
    int t = threadIdx.x;
    int c8[8];
    int own = 0;
    float ncs8[8];
    float fpart = 0.f;
    #pragma unroll
    for (int r = 0; r < 8; ++r) {
        int c = t * 8 + r;
        int v = cnt[c];
        c8[r] = v;
        own += v;
        float n = cs[c] * DECAY + (float)v * (1.0f - DECAY);
        out_ncs[c] = n;
        ncs8[r] = n;
        fpart += n;
    }
    red[t] = own;
    fred[t] = fpart;
    __syncthreads();
    for (int d = 1; d < 256; d <<= 1) {
        int v = (t >= d) ? red[t - d] : 0;
        __syncthreads();
        red[t] += v;
        __syncthreads();
    }
    for (int s = 128; s >= 1; s >>= 1) {
        if (t < s) fred[t] += fred[t + s];
        __syncthreads();
    }
    if (t == 0) s_total = fred[0];
    __syncthreads();
    int base = red[t] - own;
    float total = s_total;
    float denom = total + (float)CODES * EPSV;
    #pragma unroll
    for (int r = 0; r < 8; ++r) {
        int c = t * 8 + r;
        offsets[c] = base;
        base += c8[r];
        smoothed[c] = (ncs8[r] + EPSV) / denom * total;
    }
}

// ---------------- scatter token ids into per-code buckets --------------------
__global__ void k_scatter(const unsigned long long* __restrict__ keys,
                          const int* __restrict__ offsets, int* __restrict__ cursor,
                          int* __restrict__ list) {
    int t = blockIdx.x * blockDim.x + threadIdx.x;
    if (t >= N_TOK) return;
    int c = (int)(keys[t] & 0xFFFFFFFFULL);
    int pos = atomicAdd(cursor + c, 1);
    list[offsets[c] + pos] = t;
}

// ---------------- quantize gather: q[t] = embed[c] ---------------------------
__global__ void k_q(const float* __restrict__ embed, const unsigned long long* __restrict__ keys,
                    float* __restrict__ q) {
    int gid  = blockIdx.x * blockDim.x + threadIdx.x;
    int w    = gid >> 6;            // token
    int lane = threadIdx.x & 63;
    if (w >= N_TOK) return;
    int c = (int)(keys[w] & 0xFFFFFFFFULL);
    f32x4 e4 = reinterpret_cast<const f32x4*>(embed + (size_t)c * DIM)[lane];
    __builtin_nontemporal_store(e4, reinterpret_cast<f32x4*>(q + (size_t)w * DIM) + lane);
}

// ---------------- per-code sum of x rows + fused fin2 ------------------------
// one block (8 waves) per code; wave w sums tokens w, w+8, ...; LDS-combine.
__global__ void k_esum(const float* __restrict__ x, const int* __restrict__ cnt,
                       const int* __restrict__ offsets, const int* __restrict__ list,
                       const float* __restrict__ ea, const float* __restrict__ smoothed,
                       float* __restrict__ out_nea, float* __restrict__ out_nemb) {
    __shared__ f32x4 part[8][64];
    int c    = blockIdx.x;
    int tid  = threadIdx.x;
    int w    = tid >> 6;
    int lane = tid & 63;
    int n    = cnt[c];
    int off  = offsets[c];
    f32x4 s = (f32x4){0.f, 0.f, 0.f, 0.f};
    for (int i = w; i < n; i += 8) {
        int t = list[off + i];
        s += reinterpret_cast<const f32x4*>(x + (size_t)t * DIM)[lane];
    }
    part[w][lane] = s;
    __syncthreads();
    if (w == 0) {
        f32x4 tot = part[0][lane];
        #pragma unroll
        for (int p = 1; p < 8; ++p) tot += part[p][lane];
        size_t idx = (size_t)c * DIM + lane * 4;
        f32x4 ea4 = *reinterpret_cast<const f32x4*>(ea + idx);
        f32x4 nea;
        float inv = 1.0f / smoothed[c];
        #pragma unroll
        for (int j = 0; j < 4; ++j) nea[j] = ea4[j] * DECAY + tot[j] * (1.0f - DECAY);
        *reinterpret_cast<f32x4*>(out_nea + idx) = nea;
        f32x4 nemb;
        #pragma unroll
        for (int j = 0; j < 4; ++j) nemb[j] = nea[j] * inv;
        *reinterpret_cast<f32x4*>(out_nemb + idx) = nemb;
    }
}

extern "C" void kernel_launch(void* const* d_in, const int* in_sizes, int n_in,
                              void* d_out, int out_size, void* d_ws, size_t ws_size,
                              hipStream_t stream) {
    const float* x     = (const float*)d_in[0];
    const float* embed = (const float*)d_in[1];
    const float* eavg  = (const float*)d_in[2];
    const float* csz   = (const float*)d_in[3];
    float* out = (float*)d_out;
    char*  wsb = (char*)d_ws;

    unsigned long long* keys = (unsigned long long*)(wsb + WSB_KEYS);
    int*            cnt  = (int*)(wsb + WSB_CNT);
    int*            cur  = (int*)(wsb + WSB_CUR);
    int*            off  = (int*)(wsb + WSB_OFF);
    int*            list = (int*)(wsb + WSB_LIST);
    unsigned short* ehi  = (unsigned short*)(wsb + WSB_EHI);
    unsigned short* elo  = (unsigned short*)(wsb + WSB_ELO);
    float*          x2   = (float*)(wsb + WSB_X2);
    float*          e2   = (float*)(wsb + WSB_E2);
    float*          smoo = (float*)(wsb + WSB_SMOO);

    // x hi/lo staged in the quantize output region (same byte size); k_q
    // overwrites it AFTER k_main has consumed it (stream-ordered).
    unsigned short* xhi = (unsigned short*)(out + OUT_Q);
    unsigned short* xlo = xhi + (size_t)N_TOK * DIM;

    (void)hipMemsetAsync(wsb + WSB_KEYS, 0xFF, 524288, stream);       // keys = +inf
    (void)hipMemsetAsync(wsb + WSB_CNT, 0, 16384, stream);            // cnt + cursor = 0

    k_split<<<N_TOK * 64 / 256, 256, 0, stream>>>(x, xhi, xlo, x2, N_TOK);
    k_split<<<CODES * 64 / 256, 256, 0, stream>>>(embed, ehi, elo, e2, CODES);

    k_main<<<dim3(CODES / 128, N_TOK / 128), 256, 0, stream>>>(
        xhi, xlo, ehi, elo, x2, e2, out + OUT_DIST, keys);

    k_count<<<N_TOK / 256, 256, 0, stream>>>(keys, out + OUT_IND, cnt);
    k_scan<<<1, 256, 0, stream>>>(cnt, csz, off, out + OUT_NCS, smoo);
    k_scatter<<<N_TOK / 256, 256, 0, stream>>>(keys, off, cur, list);
    k_q<<<N_TOK * 64 / 256, 256, 0, stream>>>(embed, keys, out + OUT_Q);
    k_esum<<<CODES, 512, 0, stream>>>(x, cnt, off, list, eavg, smoo,
                                      out + OUT_NEA, out + OUT_NEMB);
}